// Round 4
// baseline (45626.102 us; speedup 1.0000x reference)
//
#include <hip/hip_runtime.h>
#include <cstdint>

// ---------------- configuration ----------------
#define HDIM 250          // hidden size
#define GDIM 1000         // 4*H gate rows
#define CH   64           // chunk length (steps) for inter-WG handoff
#define PP   4            // projection WGs per layer
#define HRING 4           // h ring depth (chunks)
#define XRING 4           // xw ring depth (chunks)
#define RPAD 1024         // padded gate-row dimension
#define NTH  512

// rec-role LDS layout: weights | h double-buffer (4 skewed segments) | reduce
#define W_LDS_QPT 19                        // LDS weight quads per thread
#define LDSW_BYTES (W_LDS_QPT * NTH * 16)   // 155648
#define HSEG 144                            // skewed segment stride (bank-offset +4/seg)
#define HBUF (4 * HSEG)                     // 576 B per h buffer
#define HB_BASE LDSW_BYTES                  // 155648
#define RED_BASE (HB_BASE + 2 * HBUF)       // 156800
#define SMEM_BYTES (RED_BASE + 1024)        // 157824 <= 163840 (160 KiB)

typedef _Float16 f16x2 __attribute__((ext_vector_type(2)));

__device__ __forceinline__ float fdot2u(uint32_t w, uint32_t h, float acc) {
#if defined(__has_builtin) && __has_builtin(__builtin_amdgcn_fdot2)
  return __builtin_amdgcn_fdot2(__builtin_bit_cast(f16x2, w),
                                __builtin_bit_cast(f16x2, h), acc, false);
#else
  f16x2 wv = __builtin_bit_cast(f16x2, w), hv = __builtin_bit_cast(f16x2, h);
  return acc + (float)wv[0] * (float)hv[0] + (float)wv[1] * (float)hv[1];
#endif
}

__device__ __forceinline__ uint32_t pkh2(float a, float b) {
  f16x2 p; p[0] = (_Float16)a; p[1] = (_Float16)b;
  return __builtin_bit_cast(uint32_t, p);
}

// pack 8 consecutive f32 weights (zero beyond HDIM / null row) into 4x fp16x2
__device__ __forceinline__ uint4 pack8q(const float* rp, int c0) {
  float c[8];
#pragma unroll
  for (int u = 0; u < 8; ++u) {
    int col = c0 + u;
    c[u] = (rp && col < HDIM) ? rp[col] : 0.f;
  }
  uint4 r;
  r.x = pkh2(c[0], c[1]); r.y = pkh2(c[2], c[3]);
  r.z = pkh2(c[4], c[5]); r.w = pkh2(c[6], c[7]);
  return r;
}

__device__ __forceinline__ float sigm(float x) {
  return 1.f / (1.f + exp2f(-1.44269504088896341f * x));
}
__device__ __forceinline__ float tanh_(float x) {
  float e = exp2f(2.88539008177792681f * x);
  return 1.f - 2.f / (e + 1.f);
}

// DPP quad_perm: 0xB1 = lane^1, 0x4E = lane^2 (within 4-lane quads)
template <int CTRL>
__device__ __forceinline__ float dppq(float v) {
  return __builtin_bit_cast(
      float, __builtin_amdgcn_update_dpp(0, __builtin_bit_cast(int, v), CTRL,
                                         0xF, 0xF, true));
}

// ---- weight storage classification: 0 = plain VGPR, 1 = AGPR, 2 = LDS ----
// per row r (8 rows) x quad k (8 quads of 8 cols):
//   r<6 : 2 VGPR | 4 AGPR | 2 LDS      r==6: 1 | 4 | 3      r==7: 1 | 3 | 4
// totals: 14 VGPR quads (56 regs), 31 AGPR quads (124 aregs), 19 LDS quads
constexpr int storf(int r, int k) {
  return (r < 6) ? (k < 2 ? 0 : (k < 6 ? 1 : 2))
                 : (r == 6 ? (k < 1 ? 0 : (k < 5 ? 1 : 2))
                           : (k < 1 ? 0 : (k < 4 ? 1 : 2)));
}
constexpr int vIdxf(int r, int k) { return r < 6 ? r * 2 + k : 12 + (r - 6); }
constexpr int aIdxf(int r, int k) {
  return r < 6 ? r * 4 + (k - 2) : (r == 6 ? 24 + (k - 1) : 28 + (k - 1));
}
constexpr int lIdxf(int r, int k) {
  return r < 6 ? r * 2 + (k - 6) : (r == 6 ? 12 + (k - 5) : 15 + (k - 4));
}

#define AWRITE(dst, src) asm("v_accvgpr_write_b32 %0, %1" : "=a"(dst) : "v"(src))
// volatile: stops LICM from hoisting 124 loop-invariant AGPR reads into VGPRs
#define AREADV(dst, src) asm volatile("v_accvgpr_read_b32 %0, %1" : "=v"(dst) : "a"(src))

// ---- compile-time-unrolled weight init: every (r,k) is a template constant ----
template <int I>
__device__ __forceinline__ void initW(uint4 (&wv)[14], uint32_t (&wa)[124],
                                      char* smem, int tid, const float* Whh,
                                      int grp, int sl) {
  if constexpr (I < 64) {
    constexpr int r = I / 8, k = I % 8;
    const int w = r >> 2, gate = r & 3;
    const int u = 2 * grp + w;
    const float* rp = (u < HDIM) ? (Whh + (size_t)(gate * HDIM + u) * HDIM) : nullptr;
    uint4 q = pack8q(rp, sl * 64 + k * 8);
    if constexpr (storf(r, k) == 0) {
      wv[vIdxf(r, k)] = q;
    } else if constexpr (storf(r, k) == 1) {
      AWRITE(wa[4 * aIdxf(r, k) + 0], q.x);
      AWRITE(wa[4 * aIdxf(r, k) + 1], q.y);
      AWRITE(wa[4 * aIdxf(r, k) + 2], q.z);
      AWRITE(wa[4 * aIdxf(r, k) + 3], q.w);
    } else {
      *(uint4*)(smem + (size_t)(lIdxf(r, k) * NTH + tid) * 16) = q;
    }
    initW<I + 1>(wv, wa, smem, tid, Whh, grp, sl);
  }
}

// ---- compile-time-unrolled dot: k outer (one h quad), r inner (8 rows) ----
template <int K, int R>
__device__ __forceinline__ void dotR(float (&acc)[8], const uint4& hq,
                                     const uint4 (&wv)[14], uint32_t (&wa)[124],
                                     const char* smem, int tid) {
  if constexpr (R < 8) {
    uint4 wq;
    if constexpr (storf(R, K) == 0) {
      wq = wv[vIdxf(R, K)];
    } else if constexpr (storf(R, K) == 1) {
      AREADV(wq.x, wa[4 * aIdxf(R, K) + 0]);
      AREADV(wq.y, wa[4 * aIdxf(R, K) + 1]);
      AREADV(wq.z, wa[4 * aIdxf(R, K) + 2]);
      AREADV(wq.w, wa[4 * aIdxf(R, K) + 3]);
    } else {
      wq = *(const uint4*)(smem + (size_t)(lIdxf(R, K) * NTH + tid) * 16);
    }
    acc[R] = fdot2u(wq.x, hq.x, acc[R]);
    acc[R] = fdot2u(wq.y, hq.y, acc[R]);
    acc[R] = fdot2u(wq.z, hq.z, acc[R]);
    acc[R] = fdot2u(wq.w, hq.w, acc[R]);
    dotR<K, R + 1>(acc, hq, wv, wa, smem, tid);
  }
}
template <int K>
__device__ __forceinline__ void dotK(float (&acc)[8], const char* hb,
                                     const uint4 (&wv)[14], uint32_t (&wa)[124],
                                     const char* smem, int tid) {
  if constexpr (K < 8) {
    const uint4 hq = *(const uint4*)(hb + K * 16);
    dotR<K, 0>(acc, hq, wv, wa, smem, tid);
    dotK<K + 1>(acc, hb, wv, wa, smem, tid);
  }
}

// lgkmcnt-only barrier: keeps global (VMEM) prefetches in flight across steps
__device__ __forceinline__ void step_barrier() {
  asm volatile("s_waitcnt lgkmcnt(0)\n\ts_barrier" ::: "memory");
}

// ---------------- flags (in d_ws, zeroed each launch) ----------------
#define F_HCNT(F, li)     (F)[(li)]
#define F_XWCON(F, li)    (F)[2 + (li)]
#define F_HDONE(F, li, p) (F)[4 + (li) * PP + (p)]
#define F_XWRDY(F, li, c) (F)[16 + (li) * 128 + (c)]

__device__ __forceinline__ int aload(int* p) {
  return __hip_atomic_load(p, __ATOMIC_RELAXED, __HIP_MEMORY_SCOPE_AGENT);
}
__device__ __forceinline__ void arel(int* p, int v) {
  __hip_atomic_store(p, v, __ATOMIC_RELEASE, __HIP_MEMORY_SCOPE_AGENT);
}
__device__ __forceinline__ void acq_fence() {
  __builtin_amdgcn_fence(__ATOMIC_ACQUIRE, "agent");
}
__device__ __forceinline__ void spin_ge(int* p, int tgt) {
  unsigned n = 0;
  while (aload(p) < tgt) {
    __builtin_amdgcn_s_sleep(2);
    if (++n > 200000000u) return;  // hang guard; result will fail visibly
  }
}

// ---------------- init: transpose Wih1/2 -> WT[li][j][RPAD], biases ----------------
__global__ void lstm_init(const float* __restrict__ Wih1, const float* __restrict__ bih1,
                          const float* __restrict__ bhh1, const float* __restrict__ Wih2,
                          const float* __restrict__ bih2, const float* __restrict__ bhh2,
                          float* __restrict__ WT, float* __restrict__ BV) {
  int idx = blockIdx.x * blockDim.x + threadIdx.x;
  int stride = gridDim.x * blockDim.x;
  for (int i = idx; i < 2 * HDIM * RPAD; i += stride) {
    int li = i / (HDIM * RPAD);
    int rem = i - li * HDIM * RPAD;
    int j = rem / RPAD, r = rem - j * RPAD;
    const float* W = li ? Wih2 : Wih1;
    WT[i] = (r < GDIM) ? W[r * HDIM + j] : 0.f;
  }
  for (int i = idx; i < 2 * RPAD; i += stride) {
    int li = i >> 10, r = i & 1023;
    const float* bi = li ? bih2 : bih1;
    const float* bh = li ? bhh2 : bhh1;
    BV[i] = (r < GDIM) ? bi[r] + bh[r] : 0.f;
  }
}

// ---------------- main persistent kernel ----------------
// blocks 0..2  : recurrent WGs (layers 0,1,2). 128 groups x 4 lanes; group owns
//                2 hidden units x 4 gates (8 rows); lane slice = 64 columns.
//                Weights: 14 quads VGPR + 31 quads AGPR (inline asm) + 19 LDS.
// blocks 3..10 : projection WGs.
__global__ void __launch_bounds__(512)
__attribute__((amdgpu_waves_per_eu(2, 2))) lstm_main(
    const float* __restrict__ x, const float* __restrict__ Wih0,
    const float* __restrict__ bih0, const float* __restrict__ bhh0,
    const float* __restrict__ Whh0, const float* __restrict__ Whh1,
    const float* __restrict__ Whh2, const float* __restrict__ Wl,
    const float* __restrict__ bl, int* __restrict__ F,
    const float* __restrict__ WT, const float* __restrict__ BV,
    float* __restrict__ hRing, float* __restrict__ xwRing,
    float* __restrict__ out, int T) {
  extern __shared__ char smem[];
  const int tid = threadIdx.x;
  const int bid = blockIdx.x;
  const int NC = T / CH;

  if (bid < 3) {
    // ================= recurrent role =================
    const int L = bid;
    const int grp = tid >> 2, sl = tid & 3;
    const bool lead = (sl < 2);
    const int uu = 2 * grp + sl;  // unit owned when lead (sl<2)

    const float* Whh = (L == 0) ? Whh0 : (L == 1) ? Whh1 : Whh2;
    uint4 wv[14];
    uint32_t wa[124];
    initW<0>(wv, wa, smem, tid, Whh, grp, sl);

    // zero both h buffers (avoid NaN garbage in padded entries 250..255)
    for (int i = tid; i < (2 * HBUF) / 4; i += NTH)
      *(uint32_t*)(smem + HB_BASE + 4 * i) = 0u;
    __syncthreads();

    const float* xwBase = xwRing + (size_t)(L > 0 ? L - 1 : 0) * XRING * CH * RPAD;
    float* hBase = hRing + (size_t)L * HRING * CH * HDIM;
    float c_st = 0.f, h_last = 0.f;

    for (int tt = 0; tt < T; ++tt) {
      const int tc = tt & (CH - 1);
      const int c = tt >> 6;
      if (tc == 0) {  // chunk boundary: wait for inputs / ring backpressure
        if (tid == 0) {
          if (L > 0) spin_ge(&F_XWRDY(F, L - 1, c), 1);
          if (L < 2 && c >= HRING) {
            int cc = c - HRING;
            spin_ge(&F_HDONE(F, L, cc % PP), cc + 1);
          }
          acq_fence();
        }
        __syncthreads();
      }

      // gate inputs for this step (issued before barrier; VMEM rides across it)
      float xw0 = 0.f, xw1 = 0.f, xw2 = 0.f, xw3 = 0.f;
      if (lead && uu < HDIM) {
        if (L == 0) {
          float xt = x[tt];
          xw0 = fmaf(xt, Wih0[uu], bih0[uu] + bhh0[uu]);
          xw1 = fmaf(xt, Wih0[250 + uu], bih0[250 + uu] + bhh0[250 + uu]);
          xw2 = fmaf(xt, Wih0[500 + uu], bih0[500 + uu] + bhh0[500 + uu]);
          xw3 = fmaf(xt, Wih0[750 + uu], bih0[750 + uu] + bhh0[750 + uu]);
        } else {
          const float* xp = xwBase + (size_t)(c & (XRING - 1)) * CH * RPAD +
                            (size_t)tc * RPAD;
          xw0 = xp[uu]; xw1 = xp[250 + uu]; xw2 = xp[500 + uu]; xw3 = xp[750 + uu];
        }
      }

      step_barrier();  // h(p) writes from previous step now visible (lgkm only)

      // dot: 8 rows x 64 cols, fp16 dot2, f32 accumulate (fully template-unrolled)
      const char* hb = smem + HB_BASE + (tt & 1) * HBUF + sl * HSEG;
      float acc[8] = {0.f, 0.f, 0.f, 0.f, 0.f, 0.f, 0.f, 0.f};
      dotK<0>(acc, hb, wv, wa, smem, tid);

      // butterfly across the 4 slice lanes (DPP, VALU pipe)
#pragma unroll
      for (int r = 0; r < 8; ++r) {
        acc[r] += dppq<0xB1>(acc[r]);
        acc[r] += dppq<0x4E>(acc[r]);
      }

      // finalize: lanes 0,1 of each quad own one unit each
      if (lead) {
        const int of = sl * 4;
        float gi = acc[of + 0] + xw0, gf = acc[of + 1] + xw1;
        float gG = acc[of + 2] + xw2, go = acc[of + 3] + xw3;
        float ii = sigm(gi), ff = sigm(gf), tg = tanh_(gG), oo = sigm(go);
        c_st = ff * c_st + ii * tg;
        float hn = oo * tanh_(c_st);
        h_last = hn;
        float hOther = dppq<0xB1>(hn);  // lane0 <- lane1's h (both active here)
        if (sl == 0) {
          // fp16 pair into next-step h buffer (skewed segment, b32 write)
          char* hw = smem + HB_BASE + ((tt + 1) & 1) * HBUF + (uu >> 6) * HSEG +
                     (uu & 63) * 2;
          *(uint32_t*)hw = pkh2(hn, hOther);
          if (L < 2 && uu < HDIM) {
            float2 hp; hp.x = hn; hp.y = hOther;
            *(float2*)(hBase + (size_t)(c & (HRING - 1)) * CH * HDIM +
                       (size_t)tc * HDIM + uu) = hp;
          }
        }
      }

      if (tc == CH - 1) {  // chunk end: full barrier (drains vmcnt) then publish
        __syncthreads();
        if (tid == 0) {
          if (L < 2) arel(&F_HCNT(F, L), c + 1);
          if (L > 0) arel(&F_XWCON(F, L - 1), c + 1);
        }
      }
    }

    if (L == 2) {  // final linear on h2[T-1]
      float* red = (float*)(smem + RED_BASE);
      if (lead && uu < HDIM) red[uu] = h_last;
      __syncthreads();
      if (tid == 0) {
        float s = bl[0];
        for (int j = 0; j < HDIM; ++j) s += red[j] * Wl[j];
        out[0] = s;
      }
    }
  } else {
    // ================= projection role =================
    const int li = (bid - 3) / PP;
    const int p = (bid - 3) % PP;
    float* ldsH = (float*)smem;  // [64][257] f32
    const int lane = tid & 63, wid = tid >> 6;
    const float* WTl = WT + (size_t)li * HDIM * RPAD;
    const float* BVl = BV + (size_t)li * RPAD;

    for (int c = p; c < NC; c += PP) {
      if (tid == 0) {
        spin_ge(&F_HCNT(F, li), c + 1);
        if (c >= XRING) spin_ge(&F_XWCON(F, li), c - XRING + 1);
        acq_fence();
      }
      __syncthreads();
      const float* hsrc = hRing + (size_t)li * HRING * CH * HDIM +
                          (size_t)(c & (HRING - 1)) * CH * HDIM;
      for (int t = wid; t < CH; t += 8)
        for (int j = lane; j < HDIM; j += 64)
          ldsH[t * 257 + j] = hsrc[t * HDIM + j];
      __syncthreads();
      if (tid == 0) arel(&F_HDONE(F, li, p), c + 1);

      float* xdst = xwRing + (size_t)li * XRING * CH * RPAD +
                    (size_t)(c & (XRING - 1)) * CH * RPAD;
      const int rb0 = wid * 128;
      for (int grpq = 0; grpq < 16; ++grpq) {
        const int rb = rb0 + grpq * 8;
        float acc[8];
#pragma unroll
        for (int u = 0; u < 8; ++u) acc[u] = 0.f;
        const float* wp = WTl + rb;
        float4 wa4 = *(const float4*)(wp);
        float4 wb4 = *(const float4*)(wp + 4);
        for (int j = 0; j < HDIM; ++j) {
          int jn = (j + 1 < HDIM) ? j + 1 : HDIM - 1;
          float4 na = *(const float4*)(wp + (size_t)jn * RPAD);
          float4 nb = *(const float4*)(wp + (size_t)jn * RPAD + 4);
          float hj = ldsH[lane * 257 + j];
          acc[0] = fmaf(wa4.x, hj, acc[0]); acc[1] = fmaf(wa4.y, hj, acc[1]);
          acc[2] = fmaf(wa4.z, hj, acc[2]); acc[3] = fmaf(wa4.w, hj, acc[3]);
          acc[4] = fmaf(wb4.x, hj, acc[4]); acc[5] = fmaf(wb4.y, hj, acc[5]);
          acc[6] = fmaf(wb4.z, hj, acc[6]); acc[7] = fmaf(wb4.w, hj, acc[7]);
          wa4 = na; wb4 = nb;
        }
#pragma unroll
        for (int u = 0; u < 8; ++u) {
          int r = rb + u;
          if (r < GDIM) xdst[(size_t)lane * RPAD + r] = acc[u] + BVl[r];
        }
      }
      __syncthreads();
      if (tid == 0) arel(&F_XWRDY(F, li, c), 1);
    }
  }
}

// ---------------- launch ----------------
extern "C" void kernel_launch(void* const* d_in, const int* in_sizes, int n_in,
                              void* d_out, int out_size, void* d_ws, size_t ws_size,
                              hipStream_t stream) {
  const float* x    = (const float*)d_in[0];
  const float* Wih0 = (const float*)d_in[1];
  const float* Whh0 = (const float*)d_in[2];
  const float* bih0 = (const float*)d_in[3];
  const float* bhh0 = (const float*)d_in[4];
  const float* Wih1 = (const float*)d_in[5];
  const float* Whh1 = (const float*)d_in[6];
  const float* bih1 = (const float*)d_in[7];
  const float* bhh1 = (const float*)d_in[8];
  const float* Wih2 = (const float*)d_in[9];
  const float* Whh2 = (const float*)d_in[10];
  const float* bih2 = (const float*)d_in[11];
  const float* bhh2 = (const float*)d_in[12];
  const float* Wl   = (const float*)d_in[13];
  const float* bl   = (const float*)d_in[14];
  const int T = in_sizes[0];

  char* ws = (char*)d_ws;
  int*   F   = (int*)ws;                                        // 4096 B flags
  float* WT  = (float*)(ws + 4096);                             // 2,048,000 B
  float* BV  = (float*)(ws + 4096 + 2048000);                   // 8,192 B
  float* hR  = (float*)(ws + 4096 + 2048000 + 8192);            // 512,000 B
  float* xwR = (float*)(ws + 4096 + 2048000 + 8192 + 512000);   // 2,097,152 B

  hipMemsetAsync(F, 0, 4096, stream);  // reset protocol state every call/replay
  lstm_init<<<256, 256, 0, stream>>>(Wih1, bih1, bhh1, Wih2, bih2, bhh2, WT, BV);
  hipFuncSetAttribute(reinterpret_cast<const void*>(lstm_main),
                      hipFuncAttributeMaxDynamicSharedMemorySize, SMEM_BYTES);
  lstm_main<<<3 + 2 * PP, 512, SMEM_BYTES, stream>>>(
      x, Wih0, bih0, bhh0, Whh0, Whh1, Whh2, Wl, bl, F, WT, BV, hR, xwR,
      (float*)d_out, T);
}

// Round 6
// 19850.101 us; speedup vs baseline: 2.2985x; 2.2985x over previous
//
#include <hip/hip_runtime.h>
#include <cstdint>

// ---------------- configuration ----------------
#define HDIM 250          // hidden size
#define GDIM 1000         // 4*H gate rows
#define CH   64           // chunk length (steps) for inter-WG handoff
#define PP   4            // projection WGs per layer
#define HRING 4           // h ring depth (chunks)
#define XRING 4           // xw ring depth (chunks)
#define RPAD 1024         // padded gate-row dimension
#define NTH  1024         // 16 waves -> forced 4 waves/SIMD -> 128-VGPR cap

// rec-role LDS: 8 weight quads/thread | h double-buffer (4 skewed segs) | reduce
#define LQ_N 8
#define LDSW_BYTES (LQ_N * NTH * 16)        // 131072
#define HSEG 144                            // skewed segment stride (banks +4/seg)
#define HBUF (4 * HSEG)                     // 576 B per h buffer
#define HB_BASE LDSW_BYTES                  // 131072
#define RED_BASE (HB_BASE + 2 * HBUF)       // 132224
#define SMEM_BYTES (RED_BASE + 1024)        // 133248 <= 163840

typedef _Float16 f16x2 __attribute__((ext_vector_type(2)));

__device__ __forceinline__ float fdot2u(uint32_t w, uint32_t h, float acc) {
#if defined(__has_builtin) && __has_builtin(__builtin_amdgcn_fdot2)
  return __builtin_amdgcn_fdot2(__builtin_bit_cast(f16x2, w),
                                __builtin_bit_cast(f16x2, h), acc, false);
#else
  f16x2 wv = __builtin_bit_cast(f16x2, w), hv = __builtin_bit_cast(f16x2, h);
  return acc + (float)wv[0] * (float)hv[0] + (float)wv[1] * (float)hv[1];
#endif
}

__device__ __forceinline__ uint32_t pkh2(float a, float b) {
  f16x2 p; p[0] = (_Float16)a; p[1] = (_Float16)b;
  return __builtin_bit_cast(uint32_t, p);
}

// pack 8 consecutive f32 weights (zero beyond HDIM / null row) into 4x fp16x2
__device__ __forceinline__ uint4 pack8q(const float* rp, int c0) {
  float c[8];
#pragma unroll
  for (int u = 0; u < 8; ++u) {
    int col = c0 + u;
    c[u] = (rp && col < HDIM) ? rp[col] : 0.f;
  }
  uint4 r;
  r.x = pkh2(c[0], c[1]); r.y = pkh2(c[2], c[3]);
  r.z = pkh2(c[4], c[5]); r.w = pkh2(c[6], c[7]);
  return r;
}

__device__ __forceinline__ float rcpf_(float x) {
#if defined(__has_builtin) && __has_builtin(__builtin_amdgcn_rcpf)
  return __builtin_amdgcn_rcpf(x);
#else
  return 1.f / x;
#endif
}
__device__ __forceinline__ float sigm(float x) {
  return rcpf_(1.f + exp2f(-1.44269504088896341f * x));
}
__device__ __forceinline__ float tanh_(float x) {
  float e = exp2f(2.88539008177792681f * x);
  return 1.f - 2.f * rcpf_(e + 1.f);
}

// DPP quad_perm: 0xB1 = lane^1, 0x4E = lane^2 (within 4-lane quads)
template <int CTRL>
__device__ __forceinline__ float dppq(float v) {
  return __builtin_bit_cast(
      float, __builtin_amdgcn_update_dpp(0, __builtin_bit_cast(int, v), CTRL,
                                         0xF, 0xF, true));
}

// lgkmcnt-only barrier: keeps global (VMEM) prefetches in flight across steps
__device__ __forceinline__ void step_barrier() {
  asm volatile("s_waitcnt lgkmcnt(0)\n\ts_barrier" ::: "memory");
}

// ---------------- flags (in d_ws, zeroed each launch) ----------------
#define F_HCNT(F, li)     (F)[(li)]
#define F_XWCON(F, li)    (F)[2 + (li)]
#define F_HDONE(F, li, p) (F)[4 + (li) * PP + (p)]
#define F_XWRDY(F, li, c) (F)[16 + (li) * 128 + (c)]

__device__ __forceinline__ int aload(int* p) {
  return __hip_atomic_load(p, __ATOMIC_RELAXED, __HIP_MEMORY_SCOPE_AGENT);
}
__device__ __forceinline__ void arel(int* p, int v) {
  __hip_atomic_store(p, v, __ATOMIC_RELEASE, __HIP_MEMORY_SCOPE_AGENT);
}
__device__ __forceinline__ void acq_fence() {
  __builtin_amdgcn_fence(__ATOMIC_ACQUIRE, "agent");
}
__device__ __forceinline__ void spin_ge(int* p, int tgt) {
  unsigned n = 0;
  while (aload(p) < tgt) {
    __builtin_amdgcn_s_sleep(2);
    if (++n > 200000000u) return;  // hang guard; result will fail visibly
  }
}

// ---------------- init: transpose Wih1/2 -> WT[li][j][RPAD], biases ----------------
__global__ void lstm_init(const float* __restrict__ Wih1, const float* __restrict__ bih1,
                          const float* __restrict__ bhh1, const float* __restrict__ Wih2,
                          const float* __restrict__ bih2, const float* __restrict__ bhh2,
                          float* __restrict__ WT, float* __restrict__ BV) {
  int idx = blockIdx.x * blockDim.x + threadIdx.x;
  int stride = gridDim.x * blockDim.x;
  for (int i = idx; i < 2 * HDIM * RPAD; i += stride) {
    int li = i / (HDIM * RPAD);
    int rem = i - li * HDIM * RPAD;
    int j = rem / RPAD, r = rem - j * RPAD;
    const float* W = li ? Wih2 : Wih1;
    WT[i] = (r < GDIM) ? W[r * HDIM + j] : 0.f;
  }
  for (int i = idx; i < 2 * RPAD; i += stride) {
    int li = i >> 10, r = i & 1023;
    const float* bi = li ? bih2 : bih1;
    const float* bh = li ? bhh2 : bhh1;
    BV[i] = (r < GDIM) ? bi[r] + bh[r] : 0.f;
  }
}

// ---------------- main persistent kernel ----------------
// blocks 0..2  : recurrent WGs (layers 0,1,2). 1024 threads = 256 groups x 4
//                lanes; group g owns hidden unit u=g (all 4 gates); lane slice
//                = 64 cols. Weights: 24 NAMED uint4 in VGPRs + 8 quads LDS.
// blocks 3..10 : projection WGs.
__global__ void __launch_bounds__(NTH) lstm_main(
    const float* __restrict__ x, const float* __restrict__ Wih0,
    const float* __restrict__ bih0, const float* __restrict__ bhh0,
    const float* __restrict__ Whh0, const float* __restrict__ Whh1,
    const float* __restrict__ Whh2, const float* __restrict__ Wl,
    const float* __restrict__ bl, int* __restrict__ F,
    const float* __restrict__ WT, const float* __restrict__ BV,
    float* __restrict__ hRing, float* __restrict__ xwRing,
    float* __restrict__ out, int T) {
  extern __shared__ char smem[];
  const int tid = threadIdx.x;
  const int bid = blockIdx.x;
  const int NC = T / CH;

  if (bid < 3) {
    // ================= recurrent role =================
    const int L = bid;
    const int u = tid >> 2, sl = tid & 3;
    const bool uok = (u < HDIM);
    const int r_abs = sl * HDIM + u;  // this lane's xw gate-row

    const float* Whh = (L == 0) ? Whh0 : (L == 1) ? Whh1 : Whh2;
    char* lw = smem + tid * 16;
#define LWADDR(lq) (lw + (size_t)(lq) * (NTH * 16))
#define ROWP(r) (uok ? (Whh + ((size_t)(r) * HDIM + u) * HDIM) : (const float*)nullptr)

    // 24 named weight quads (rows = gates i,f,g,o; k = 8-col quads 0..5)
    uint4 w00, w01, w02, w03, w04, w05;
    uint4 w10, w11, w12, w13, w14, w15;
    uint4 w20, w21, w22, w23, w24, w25;
    uint4 w30, w31, w32, w33, w34, w35;
#define INITROW(r)                                          \
  w##r##0 = pack8q(ROWP(r), sl * 64 + 0);                   \
  w##r##1 = pack8q(ROWP(r), sl * 64 + 8);                   \
  w##r##2 = pack8q(ROWP(r), sl * 64 + 16);                  \
  w##r##3 = pack8q(ROWP(r), sl * 64 + 24);                  \
  w##r##4 = pack8q(ROWP(r), sl * 64 + 32);                  \
  w##r##5 = pack8q(ROWP(r), sl * 64 + 40);                  \
  *(uint4*)LWADDR(2 * (r)) = pack8q(ROWP(r), sl * 64 + 48); \
  *(uint4*)LWADDR(2 * (r) + 1) = pack8q(ROWP(r), sl * 64 + 56);
    INITROW(0) INITROW(1) INITROW(2) INITROW(3)

    // L0 per-lane input-projection scalars (x is scalar per step)
    float w0_ = 0.f, b0_ = 0.f;
    if (L == 0 && uok) {
      w0_ = Wih0[r_abs];
      b0_ = bih0[r_abs] + bhh0[r_abs];
    }

    // zero both h buffers (incl. padded cols 250..255)
    for (int i = tid; i < (2 * HBUF) / 4; i += NTH)
      *(uint32_t*)(smem + HB_BASE + 4 * i) = 0u;
    __syncthreads();

    const float* xwBase = xwRing + (size_t)(L > 0 ? L - 1 : 0) * XRING * CH * RPAD;
    float* hBase = hRing + (size_t)L * HRING * CH * HDIM;
    float c_st = 0.f, h_last = 0.f;

    for (int tt = 0; tt < T; ++tt) {
      const int tc = tt & (CH - 1);
      const int c = tt >> 6;
      if (tc == 0) {  // chunk boundary: wait for inputs / ring backpressure
        if (tid == 0) {
          if (L > 0) spin_ge(&F_XWRDY(F, L - 1, c), 1);
          if (L < 2 && c >= HRING) {
            int cc = c - HRING;
            spin_ge(&F_HDONE(F, L, cc % PP), cc + 1);
          }
          acq_fence();
        }
        __syncthreads();
      }

      // this lane's gate input (VMEM issued early, consumed after the dot)
      float xw = 0.f;
      if (uok) {
        if (L == 0) {
          xw = fmaf(x[tt], w0_, b0_);
        } else {
          const float* xp = xwBase + (size_t)(c & (XRING - 1)) * CH * RPAD +
                            (size_t)tc * RPAD;
          xw = xp[r_abs];
        }
      }

      // dot: 4 gate rows x 64-col slice, fp16 dot2, f32 accumulate
      const char* hb = smem + HB_BASE + (tt & 1) * HBUF + sl * HSEG;
      float a0 = 0.f, a1 = 0.f, a2 = 0.f, a3 = 0.f;
#define FD4(W_, H_, A_)                \
  A_ = fdot2u((W_).x, (H_).x, A_);     \
  A_ = fdot2u((W_).y, (H_).y, A_);     \
  A_ = fdot2u((W_).z, (H_).z, A_);     \
  A_ = fdot2u((W_).w, (H_).w, A_);
#define DOTK(k)                                      \
  {                                                  \
    const uint4 hq = *(const uint4*)(hb + (k) * 16); \
    FD4(w0##k, hq, a0)                               \
    FD4(w1##k, hq, a1)                               \
    FD4(w2##k, hq, a2)                               \
    FD4(w3##k, hq, a3)                               \
  }
      DOTK(0) DOTK(1) DOTK(2) DOTK(3) DOTK(4) DOTK(5)
      {
        const uint4 hq = *(const uint4*)(hb + 96);
        uint4 q;
        q = *(const uint4*)LWADDR(0); FD4(q, hq, a0)
        q = *(const uint4*)LWADDR(2); FD4(q, hq, a1)
        q = *(const uint4*)LWADDR(4); FD4(q, hq, a2)
        q = *(const uint4*)LWADDR(6); FD4(q, hq, a3)
      }
      {
        const uint4 hq = *(const uint4*)(hb + 112);
        uint4 q;
        q = *(const uint4*)LWADDR(1); FD4(q, hq, a0)
        q = *(const uint4*)LWADDR(3); FD4(q, hq, a1)
        q = *(const uint4*)LWADDR(5); FD4(q, hq, a2)
        q = *(const uint4*)LWADDR(7); FD4(q, hq, a3)
      }

      // add xw into the gate row this lane owns, then butterfly over 4 lanes
      a0 += (sl == 0) ? xw : 0.f;
      a1 += (sl == 1) ? xw : 0.f;
      a2 += (sl == 2) ? xw : 0.f;
      a3 += (sl == 3) ? xw : 0.f;
      a0 += dppq<0xB1>(a0); a0 += dppq<0x4E>(a0);
      a1 += dppq<0xB1>(a1); a1 += dppq<0x4E>(a1);
      a2 += dppq<0xB1>(a2); a2 += dppq<0x4E>(a2);
      a3 += dppq<0xB1>(a3); a3 += dppq<0x4E>(a3);

      // update (all 4 lanes redundantly; consistent deterministic math)
      float ii = sigm(a0), ff = sigm(a1), tg = tanh_(a2), oo = sigm(a3);
      c_st = ff * c_st + ii * tg;
      float hn = oo * tanh_(c_st);
      h_last = hn;

      if (sl == 0 && uok) {
        // fp16 h into next-step buffer (segment u>>6, skewed)
        char* hw = smem + HB_BASE + ((tt + 1) & 1) * HBUF + (u >> 6) * HSEG +
                   (u & 63) * 2;
        *(_Float16*)hw = (_Float16)hn;
        if (L < 2)
          hBase[(size_t)(c & (HRING - 1)) * CH * HDIM + (size_t)tc * HDIM + u] = hn;
      }

      if (tc == CH - 1) {  // chunk end: full barrier (drains vmcnt) then publish
        __syncthreads();
        if (tid == 0) {
          if (L < 2) arel(&F_HCNT(F, L), c + 1);
          if (L > 0) arel(&F_XWCON(F, L - 1), c + 1);
        }
      } else {
        step_barrier();  // h(next) writes visible; lgkm-only
      }
    }

    if (L == 2) {  // final linear on h2[T-1]
      float* red = (float*)(smem + RED_BASE);
      if (sl == 0 && uok) red[u] = h_last;
      __syncthreads();
      if (tid == 0) {
        float s = bl[0];
        for (int j = 0; j < HDIM; ++j) s += red[j] * Wl[j];
        out[0] = s;
      }
    }
  } else {
    // ================= projection role (1024 threads, 16 waves) =================
    const int li = (bid - 3) / PP;
    const int p = (bid - 3) % PP;
    float* ldsH = (float*)smem;  // [64][257] f32
    const int lane = tid & 63, wid = tid >> 6;
    const float* WTl = WT + (size_t)li * HDIM * RPAD;
    const float* BVl = BV + (size_t)li * RPAD;

    for (int c = p; c < NC; c += PP) {
      if (tid == 0) {
        spin_ge(&F_HCNT(F, li), c + 1);
        if (c >= XRING) spin_ge(&F_XWCON(F, li), c - XRING + 1);
        acq_fence();
      }
      __syncthreads();
      const float* hsrc = hRing + (size_t)li * HRING * CH * HDIM +
                          (size_t)(c & (HRING - 1)) * CH * HDIM;
      for (int t = wid; t < CH; t += 16)
        for (int j = lane; j < HDIM; j += 64)
          ldsH[t * 257 + j] = hsrc[t * HDIM + j];
      __syncthreads();
      if (tid == 0) arel(&F_HDONE(F, li, p), c + 1);

      float* xdst = xwRing + (size_t)li * XRING * CH * RPAD +
                    (size_t)(c & (XRING - 1)) * CH * RPAD;
      const int rb0 = wid * 64;  // 16 waves x 64 rows = 1024 padded rows
      for (int grpq = 0; grpq < 8; ++grpq) {
        const int rb = rb0 + grpq * 8;
        float acc[8];
#pragma unroll
        for (int uq = 0; uq < 8; ++uq) acc[uq] = 0.f;
        const float* wp = WTl + rb;
        float4 wa4 = *(const float4*)(wp);
        float4 wb4 = *(const float4*)(wp + 4);
        for (int j = 0; j < HDIM; ++j) {
          int jn = (j + 1 < HDIM) ? j + 1 : HDIM - 1;
          float4 na = *(const float4*)(wp + (size_t)jn * RPAD);
          float4 nb = *(const float4*)(wp + (size_t)jn * RPAD + 4);
          float hj = ldsH[lane * 257 + j];
          acc[0] = fmaf(wa4.x, hj, acc[0]); acc[1] = fmaf(wa4.y, hj, acc[1]);
          acc[2] = fmaf(wa4.z, hj, acc[2]); acc[3] = fmaf(wa4.w, hj, acc[3]);
          acc[4] = fmaf(wb4.x, hj, acc[4]); acc[5] = fmaf(wb4.y, hj, acc[5]);
          acc[6] = fmaf(wb4.z, hj, acc[6]); acc[7] = fmaf(wb4.w, hj, acc[7]);
          wa4 = na; wb4 = nb;
        }
#pragma unroll
        for (int uq = 0; uq < 8; ++uq) {
          int r = rb + uq;
          if (r < GDIM) xdst[(size_t)lane * RPAD + r] = acc[uq] + BVl[r];
        }
      }
      __syncthreads();
      if (tid == 0) arel(&F_XWRDY(F, li, c), 1);
    }
  }
}

// ---------------- launch ----------------
extern "C" void kernel_launch(void* const* d_in, const int* in_sizes, int n_in,
                              void* d_out, int out_size, void* d_ws, size_t ws_size,
                              hipStream_t stream) {
  const float* x    = (const float*)d_in[0];
  const float* Wih0 = (const float*)d_in[1];
  const float* Whh0 = (const float*)d_in[2];
  const float* bih0 = (const float*)d_in[3];
  const float* bhh0 = (const float*)d_in[4];
  const float* Wih1 = (const float*)d_in[5];
  const float* Whh1 = (const float*)d_in[6];
  const float* bih1 = (const float*)d_in[7];
  const float* bhh1 = (const float*)d_in[8];
  const float* Wih2 = (const float*)d_in[9];
  const float* Whh2 = (const float*)d_in[10];
  const float* bih2 = (const float*)d_in[11];
  const float* bhh2 = (const float*)d_in[12];
  const float* Wl   = (const float*)d_in[13];
  const float* bl   = (const float*)d_in[14];
  const int T = in_sizes[0];

  char* ws = (char*)d_ws;
  int*   F   = (int*)ws;                                        // 4096 B flags
  float* WT  = (float*)(ws + 4096);                             // 2,048,000 B
  float* BV  = (float*)(ws + 4096 + 2048000);                   // 8,192 B
  float* hR  = (float*)(ws + 4096 + 2048000 + 8192);            // 512,000 B
  float* xwR = (float*)(ws + 4096 + 2048000 + 8192 + 512000);   // 2,097,152 B

  hipMemsetAsync(F, 0, 4096, stream);  // reset protocol state every call/replay
  lstm_init<<<256, 256, 0, stream>>>(Wih1, bih1, bhh1, Wih2, bih2, bhh2, WT, BV);
  hipFuncSetAttribute(reinterpret_cast<const void*>(lstm_main),
                      hipFuncAttributeMaxDynamicSharedMemorySize, SMEM_BYTES);
  lstm_main<<<3 + 2 * PP, NTH, SMEM_BYTES, stream>>>(
      x, Wih0, bih0, bhh0, Whh0, Whh1, Whh2, Wl, bl, F, WT, BV, hR, xwR,
      (float*)d_out, T);
}

// Round 7
// 19820.692 us; speedup vs baseline: 2.3019x; 1.0015x over previous
//
#include <hip/hip_runtime.h>
#include <cstdint>

// ---------------- configuration ----------------
#define HDIM 250          // hidden size
#define GDIM 1000         // 4*H gate rows
#define CH   64           // chunk length (steps) for inter-WG handoff
#define PP   4            // projection WGs per layer
#define HRING 4           // h ring depth (chunks)
#define XRING 4           // xw ring depth (chunks)
#define RPAD 1024         // padded gate-row dimension
#define NTH  1024

// rec-role LDS: 8 weight quads/thread | h double-buffer (4 skewed segs) | reduce
#define LQ_N 8
#define LDSW_BYTES (LQ_N * NTH * 16)        // 131072
#define HSEG 144                            // skewed segment stride (banks +4/seg)
#define HBUF (4 * HSEG)                     // 576 B per h buffer
#define HB_BASE LDSW_BYTES                  // 131072
#define RED_BASE (HB_BASE + 2 * HBUF)       // 132224
#define SMEM_BYTES (RED_BASE + 1024)        // 133248 <= 163840
// STATIC shared memory: compiler sees 133 KB -> knows 1 WG/CU -> register
// budget becomes need-driven (the extern/dynamic variant assumed LDS~0,
// targeted 2 WG/CU, and capped VGPRs at 64/128 -> weights spilled to scratch).

typedef _Float16 f16x2 __attribute__((ext_vector_type(2)));

__device__ __forceinline__ float fdot2u(uint32_t w, uint32_t h, float acc) {
#if defined(__has_builtin) && __has_builtin(__builtin_amdgcn_fdot2)
  return __builtin_amdgcn_fdot2(__builtin_bit_cast(f16x2, w),
                                __builtin_bit_cast(f16x2, h), acc, false);
#else
  f16x2 wv = __builtin_bit_cast(f16x2, w), hv = __builtin_bit_cast(f16x2, h);
  return acc + (float)wv[0] * (float)hv[0] + (float)wv[1] * (float)hv[1];
#endif
}

__device__ __forceinline__ uint32_t pkh2(float a, float b) {
  f16x2 p; p[0] = (_Float16)a; p[1] = (_Float16)b;
  return __builtin_bit_cast(uint32_t, p);
}

// pack 8 consecutive f32 weights (zero beyond HDIM / null row) into 4x fp16x2
__device__ __forceinline__ uint4 pack8q(const float* rp, int c0) {
  float c[8];
#pragma unroll
  for (int u = 0; u < 8; ++u) {
    int col = c0 + u;
    c[u] = (rp && col < HDIM) ? rp[col] : 0.f;
  }
  uint4 r;
  r.x = pkh2(c[0], c[1]); r.y = pkh2(c[2], c[3]);
  r.z = pkh2(c[4], c[5]); r.w = pkh2(c[6], c[7]);
  return r;
}

__device__ __forceinline__ float rcpf_(float x) {
#if defined(__has_builtin) && __has_builtin(__builtin_amdgcn_rcpf)
  return __builtin_amdgcn_rcpf(x);
#else
  return 1.f / x;
#endif
}
__device__ __forceinline__ float sigm(float x) {
  return rcpf_(1.f + exp2f(-1.44269504088896341f * x));
}
__device__ __forceinline__ float tanh_(float x) {
  float e = exp2f(2.88539008177792681f * x);
  return 1.f - 2.f * rcpf_(e + 1.f);
}

// DPP quad_perm: 0xB1 = lane^1, 0x4E = lane^2 (within 4-lane quads)
template <int CTRL>
__device__ __forceinline__ float dppq(float v) {
  return __builtin_bit_cast(
      float, __builtin_amdgcn_update_dpp(0, __builtin_bit_cast(int, v), CTRL,
                                         0xF, 0xF, true));
}

// lgkmcnt-only barrier: keeps global (VMEM) prefetches in flight across steps
__device__ __forceinline__ void step_barrier() {
  asm volatile("s_waitcnt lgkmcnt(0)\n\ts_barrier" ::: "memory");
}

// ---------------- flags (in d_ws, zeroed each launch) ----------------
#define F_HCNT(F, li)     (F)[(li)]
#define F_XWCON(F, li)    (F)[2 + (li)]
#define F_HDONE(F, li, p) (F)[4 + (li) * PP + (p)]
#define F_XWRDY(F, li, c) (F)[16 + (li) * 128 + (c)]

__device__ __forceinline__ int aload(int* p) {
  return __hip_atomic_load(p, __ATOMIC_RELAXED, __HIP_MEMORY_SCOPE_AGENT);
}
__device__ __forceinline__ void arel(int* p, int v) {
  __hip_atomic_store(p, v, __ATOMIC_RELEASE, __HIP_MEMORY_SCOPE_AGENT);
}
__device__ __forceinline__ void acq_fence() {
  __builtin_amdgcn_fence(__ATOMIC_ACQUIRE, "agent");
}
__device__ __forceinline__ void spin_ge(int* p, int tgt) {
  unsigned n = 0;
  while (aload(p) < tgt) {
    __builtin_amdgcn_s_sleep(2);
    if (++n > 200000000u) return;  // hang guard; result will fail visibly
  }
}

// ---------------- init: transpose Wih1/2 -> WT[li][j][RPAD], biases ----------------
__global__ void lstm_init(const float* __restrict__ Wih1, const float* __restrict__ bih1,
                          const float* __restrict__ bhh1, const float* __restrict__ Wih2,
                          const float* __restrict__ bih2, const float* __restrict__ bhh2,
                          float* __restrict__ WT, float* __restrict__ BV) {
  int idx = blockIdx.x * blockDim.x + threadIdx.x;
  int stride = gridDim.x * blockDim.x;
  for (int i = idx; i < 2 * HDIM * RPAD; i += stride) {
    int li = i / (HDIM * RPAD);
    int rem = i - li * HDIM * RPAD;
    int j = rem / RPAD, r = rem - j * RPAD;
    const float* W = li ? Wih2 : Wih1;
    WT[i] = (r < GDIM) ? W[r * HDIM + j] : 0.f;
  }
  for (int i = idx; i < 2 * RPAD; i += stride) {
    int li = i >> 10, r = i & 1023;
    const float* bi = li ? bih2 : bih1;
    const float* bh = li ? bhh2 : bhh1;
    BV[i] = (r < GDIM) ? bi[r] + bh[r] : 0.f;
  }
}

// ---------------- main persistent kernel ----------------
// blocks 0..2  : recurrent WGs (layers 0,1,2). 1024 threads = 256 groups x 4
//                lanes; group g owns hidden unit u=g (all 4 gates); lane slice
//                = 64 cols. Weights: 24 NAMED uint4 in VGPRs + 8 quads LDS.
// blocks 3..10 : projection WGs.
__global__ void __launch_bounds__(NTH) lstm_main(
    const float* __restrict__ x, const float* __restrict__ Wih0,
    const float* __restrict__ bih0, const float* __restrict__ bhh0,
    const float* __restrict__ Whh0, const float* __restrict__ Whh1,
    const float* __restrict__ Whh2, const float* __restrict__ Wl,
    const float* __restrict__ bl, int* __restrict__ F,
    const float* __restrict__ WT, const float* __restrict__ BV,
    float* __restrict__ hRing, float* __restrict__ xwRing,
    float* __restrict__ out, int T) {
  __shared__ __align__(16) char smem[SMEM_BYTES];
  const int tid = threadIdx.x;
  const int bid = blockIdx.x;
  const int NC = T / CH;

  if (bid < 3) {
    // ================= recurrent role =================
    const int L = bid;
    const int u = tid >> 2, sl = tid & 3;
    const bool uok = (u < HDIM);
    const int r_abs = sl * HDIM + u;  // this lane's xw gate-row

    const float* Whh = (L == 0) ? Whh0 : (L == 1) ? Whh1 : Whh2;
    char* lw = smem + tid * 16;
#define LWADDR(lq) (lw + (size_t)(lq) * (NTH * 16))
#define ROWP(r) (uok ? (Whh + ((size_t)(r) * HDIM + u) * HDIM) : (const float*)nullptr)

    // 24 named weight quads (rows = gates i,f,g,o; k = 8-col quads 0..5)
    uint4 w00, w01, w02, w03, w04, w05;
    uint4 w10, w11, w12, w13, w14, w15;
    uint4 w20, w21, w22, w23, w24, w25;
    uint4 w30, w31, w32, w33, w34, w35;
#define INITROW(r)                                          \
  w##r##0 = pack8q(ROWP(r), sl * 64 + 0);                   \
  w##r##1 = pack8q(ROWP(r), sl * 64 + 8);                   \
  w##r##2 = pack8q(ROWP(r), sl * 64 + 16);                  \
  w##r##3 = pack8q(ROWP(r), sl * 64 + 24);                  \
  w##r##4 = pack8q(ROWP(r), sl * 64 + 32);                  \
  w##r##5 = pack8q(ROWP(r), sl * 64 + 40);                  \
  *(uint4*)LWADDR(2 * (r)) = pack8q(ROWP(r), sl * 64 + 48); \
  *(uint4*)LWADDR(2 * (r) + 1) = pack8q(ROWP(r), sl * 64 + 56);
    INITROW(0) INITROW(1) INITROW(2) INITROW(3)

    // L0 per-lane input-projection scalars (x is scalar per step)
    float w0_ = 0.f, b0_ = 0.f;
    if (L == 0 && uok) {
      w0_ = Wih0[r_abs];
      b0_ = bih0[r_abs] + bhh0[r_abs];
    }

    // zero both h buffers (incl. padded cols 250..255)
    for (int i = tid; i < (2 * HBUF) / 4; i += NTH)
      *(uint32_t*)(smem + HB_BASE + 4 * i) = 0u;
    __syncthreads();

    const float* xwBase = xwRing + (size_t)(L > 0 ? L - 1 : 0) * XRING * CH * RPAD;
    float* hBase = hRing + (size_t)L * HRING * CH * HDIM;
    float c_st = 0.f, h_last = 0.f;

    for (int tt = 0; tt < T; ++tt) {
      const int tc = tt & (CH - 1);
      const int c = tt >> 6;
      if (tc == 0) {  // chunk boundary: wait for inputs / ring backpressure
        if (tid == 0) {
          if (L > 0) spin_ge(&F_XWRDY(F, L - 1, c), 1);
          if (L < 2 && c >= HRING) {
            int cc = c - HRING;
            spin_ge(&F_HDONE(F, L, cc % PP), cc + 1);
          }
          acq_fence();
        }
        __syncthreads();
      }

      // this lane's gate input (VMEM issued early, consumed after the dot)
      float xw = 0.f;
      if (uok) {
        if (L == 0) {
          xw = fmaf(x[tt], w0_, b0_);
        } else {
          const float* xp = xwBase + (size_t)(c & (XRING - 1)) * CH * RPAD +
                            (size_t)tc * RPAD;
          xw = xp[r_abs];
        }
      }

      // dot: 4 gate rows x 64-col slice, fp16 dot2, f32 accumulate
      const char* hb = smem + HB_BASE + (tt & 1) * HBUF + sl * HSEG;
      float a0 = 0.f, a1 = 0.f, a2 = 0.f, a3 = 0.f;
#define FD4(W_, H_, A_)                \
  A_ = fdot2u((W_).x, (H_).x, A_);     \
  A_ = fdot2u((W_).y, (H_).y, A_);     \
  A_ = fdot2u((W_).z, (H_).z, A_);     \
  A_ = fdot2u((W_).w, (H_).w, A_);
#define DOTK(k)                                      \
  {                                                  \
    const uint4 hq = *(const uint4*)(hb + (k) * 16); \
    FD4(w0##k, hq, a0)                               \
    FD4(w1##k, hq, a1)                               \
    FD4(w2##k, hq, a2)                               \
    FD4(w3##k, hq, a3)                               \
  }
      DOTK(0) DOTK(1) DOTK(2) DOTK(3) DOTK(4) DOTK(5)
      {
        const uint4 hq = *(const uint4*)(hb + 96);
        uint4 q;
        q = *(const uint4*)LWADDR(0); FD4(q, hq, a0)
        q = *(const uint4*)LWADDR(2); FD4(q, hq, a1)
        q = *(const uint4*)LWADDR(4); FD4(q, hq, a2)
        q = *(const uint4*)LWADDR(6); FD4(q, hq, a3)
      }
      {
        const uint4 hq = *(const uint4*)(hb + 112);
        uint4 q;
        q = *(const uint4*)LWADDR(1); FD4(q, hq, a0)
        q = *(const uint4*)LWADDR(3); FD4(q, hq, a1)
        q = *(const uint4*)LWADDR(5); FD4(q, hq, a2)
        q = *(const uint4*)LWADDR(7); FD4(q, hq, a3)
      }

      // add xw into the gate row this lane owns, then butterfly over 4 lanes
      a0 += (sl == 0) ? xw : 0.f;
      a1 += (sl == 1) ? xw : 0.f;
      a2 += (sl == 2) ? xw : 0.f;
      a3 += (sl == 3) ? xw : 0.f;
      a0 += dppq<0xB1>(a0); a0 += dppq<0x4E>(a0);
      a1 += dppq<0xB1>(a1); a1 += dppq<0x4E>(a1);
      a2 += dppq<0xB1>(a2); a2 += dppq<0x4E>(a2);
      a3 += dppq<0xB1>(a3); a3 += dppq<0x4E>(a3);

      // update (all 4 lanes redundantly; consistent deterministic math)
      float ii = sigm(a0), ff = sigm(a1), tg = tanh_(a2), oo = sigm(a3);
      c_st = ff * c_st + ii * tg;
      float hn = oo * tanh_(c_st);
      h_last = hn;

      if (sl == 0 && uok) {
        // fp16 h into next-step buffer (segment u>>6, skewed)
        char* hw = smem + HB_BASE + ((tt + 1) & 1) * HBUF + (u >> 6) * HSEG +
                   (u & 63) * 2;
        *(_Float16*)hw = (_Float16)hn;
        if (L < 2)
          hBase[(size_t)(c & (HRING - 1)) * CH * HDIM + (size_t)tc * HDIM + u] = hn;
      }

      if (tc == CH - 1) {  // chunk end: full barrier (drains vmcnt) then publish
        __syncthreads();
        if (tid == 0) {
          if (L < 2) arel(&F_HCNT(F, L), c + 1);
          if (L > 0) arel(&F_XWCON(F, L - 1), c + 1);
        }
      } else {
        step_barrier();  // h(next) writes visible; lgkm-only
      }
    }

    if (L == 2) {  // final linear on h2[T-1]
      float* red = (float*)(smem + RED_BASE);
      if (sl == 0 && uok) red[u] = h_last;
      __syncthreads();
      if (tid == 0) {
        float s = bl[0];
        for (int j = 0; j < HDIM; ++j) s += red[j] * Wl[j];
        out[0] = s;
      }
    }
  } else {
    // ================= projection role (1024 threads, 16 waves) =================
    const int li = (bid - 3) / PP;
    const int p = (bid - 3) % PP;
    float* ldsH = (float*)smem;  // [64][257] f32
    const int lane = tid & 63, wid = tid >> 6;
    const float* WTl = WT + (size_t)li * HDIM * RPAD;
    const float* BVl = BV + (size_t)li * RPAD;

    for (int c = p; c < NC; c += PP) {
      if (tid == 0) {
        spin_ge(&F_HCNT(F, li), c + 1);
        if (c >= XRING) spin_ge(&F_XWCON(F, li), c - XRING + 1);
        acq_fence();
      }
      __syncthreads();
      const float* hsrc = hRing + (size_t)li * HRING * CH * HDIM +
                          (size_t)(c & (HRING - 1)) * CH * HDIM;
      for (int t = wid; t < CH; t += 16)
        for (int j = lane; j < HDIM; j += 64)
          ldsH[t * 257 + j] = hsrc[t * HDIM + j];
      __syncthreads();
      if (tid == 0) arel(&F_HDONE(F, li, p), c + 1);

      float* xdst = xwRing + (size_t)li * XRING * CH * RPAD +
                    (size_t)(c & (XRING - 1)) * CH * RPAD;
      const int rb0 = wid * 64;  // 16 waves x 64 rows = 1024 padded rows
      for (int grpq = 0; grpq < 8; ++grpq) {
        const int rb = rb0 + grpq * 8;
        float acc[8];
#pragma unroll
        for (int uq = 0; uq < 8; ++uq) acc[uq] = 0.f;
        const float* wp = WTl + rb;
        float4 wa4 = *(const float4*)(wp);
        float4 wb4 = *(const float4*)(wp + 4);
        for (int j = 0; j < HDIM; ++j) {
          int jn = (j + 1 < HDIM) ? j + 1 : HDIM - 1;
          float4 na = *(const float4*)(wp + (size_t)jn * RPAD);
          float4 nb = *(const float4*)(wp + (size_t)jn * RPAD + 4);
          float hj = ldsH[lane * 257 + j];
          acc[0] = fmaf(wa4.x, hj, acc[0]); acc[1] = fmaf(wa4.y, hj, acc[1]);
          acc[2] = fmaf(wa4.z, hj, acc[2]); acc[3] = fmaf(wa4.w, hj, acc[3]);
          acc[4] = fmaf(wb4.x, hj, acc[4]); acc[5] = fmaf(wb4.y, hj, acc[5]);
          acc[6] = fmaf(wb4.z, hj, acc[6]); acc[7] = fmaf(wb4.w, hj, acc[7]);
          wa4 = na; wb4 = nb;
        }
#pragma unroll
        for (int uq = 0; uq < 8; ++uq) {
          int r = rb + uq;
          if (r < GDIM) xdst[(size_t)lane * RPAD + r] = acc[uq] + BVl[r];
        }
      }
      __syncthreads();
      if (tid == 0) arel(&F_XWRDY(F, li, c), 1);
    }
  }
}

// ---------------- launch ----------------
extern "C" void kernel_launch(void* const* d_in, const int* in_sizes, int n_in,
                              void* d_out, int out_size, void* d_ws, size_t ws_size,
                              hipStream_t stream) {
  const float* x    = (const float*)d_in[0];
  const float* Wih0 = (const float*)d_in[1];
  const float* Whh0 = (const float*)d_in[2];
  const float* bih0 = (const float*)d_in[3];
  const float* bhh0 = (const float*)d_in[4];
  const float* Wih1 = (const float*)d_in[5];
  const float* Whh1 = (const float*)d_in[6];
  const float* bih1 = (const float*)d_in[7];
  const float* bhh1 = (const float*)d_in[8];
  const float* Wih2 = (const float*)d_in[9];
  const float* Whh2 = (const float*)d_in[10];
  const float* bih2 = (const float*)d_in[11];
  const float* bhh2 = (const float*)d_in[12];
  const float* Wl   = (const float*)d_in[13];
  const float* bl   = (const float*)d_in[14];
  const int T = in_sizes[0];

  char* ws = (char*)d_ws;
  int*   F   = (int*)ws;                                        // 4096 B flags
  float* WT  = (float*)(ws + 4096);                             // 2,048,000 B
  float* BV  = (float*)(ws + 4096 + 2048000);                   // 8,192 B
  float* hR  = (float*)(ws + 4096 + 2048000 + 8192);            // 512,000 B
  float* xwR = (float*)(ws + 4096 + 2048000 + 8192 + 512000);   // 2,097,152 B

  hipMemsetAsync(F, 0, 4096, stream);  // reset protocol state every call/replay
  lstm_init<<<256, 256, 0, stream>>>(Wih1, bih1, bhh1, Wih2, bih2, bhh2, WT, BV);
  lstm_main<<<3 + 2 * PP, NTH, 0, stream>>>(
      x, Wih0, bih0, bhh0, Whh0, Whh1, Whh2, Wl, bl, F, WT, BV, hR, xwR,
      (float*)d_out, T);
}

// Round 8
// 19817.929 us; speedup vs baseline: 2.3023x; 1.0001x over previous
//
#include <hip/hip_runtime.h>
#include <cstdint>

// ---------------- configuration ----------------
#define HDIM 250          // hidden size
#define GDIM 1000         // 4*H gate rows
#define CH   64           // chunk length (steps) for inter-WG handoff
#define PP   4            // projection WGs per layer
#define HRING 4           // h ring depth (chunks)
#define XRING 4           // xw ring depth (chunks)
#define RPAD 1024         // padded gate-row dimension
#define NTH  1024

// rec-role LDS: 8 weight quads/thread | h double-buffer (4 skewed segs) | reduce
#define LQ_N 8
#define LDSW_BYTES (LQ_N * NTH * 16)        // 131072
#define HSEG 144                            // skewed segment stride (banks +4/seg)
#define HBUF (4 * HSEG)                     // 576 B per h buffer
#define HB_BASE LDSW_BYTES                  // 131072
#define RED_BASE (HB_BASE + 2 * HBUF)       // 132224
#define SMEM_BYTES (RED_BASE + 1024)        // 133248 <= 163840 -> 1 WG/CU

typedef _Float16 f16x2 __attribute__((ext_vector_type(2)));

__device__ __forceinline__ float fdot2u(uint32_t w, uint32_t h, float acc) {
#if defined(__has_builtin) && __has_builtin(__builtin_amdgcn_fdot2)
  return __builtin_amdgcn_fdot2(__builtin_bit_cast(f16x2, w),
                                __builtin_bit_cast(f16x2, h), acc, false);
#else
  f16x2 wv = __builtin_bit_cast(f16x2, w), hv = __builtin_bit_cast(f16x2, h);
  return acc + (float)wv[0] * (float)hv[0] + (float)wv[1] * (float)hv[1];
#endif
}

__device__ __forceinline__ uint32_t pkh2(float a, float b) {
  f16x2 p; p[0] = (_Float16)a; p[1] = (_Float16)b;
  return __builtin_bit_cast(uint32_t, p);
}

// pack 8 consecutive f32 weights (zero beyond HDIM / null row) into 4x fp16x2
__device__ __forceinline__ uint4 pack8q(const float* rp, int c0) {
  float c[8];
#pragma unroll
  for (int u = 0; u < 8; ++u) {
    int col = c0 + u;
    c[u] = (rp && col < HDIM) ? rp[col] : 0.f;
  }
  uint4 r;
  r.x = pkh2(c[0], c[1]); r.y = pkh2(c[2], c[3]);
  r.z = pkh2(c[4], c[5]); r.w = pkh2(c[6], c[7]);
  return r;
}

__device__ __forceinline__ float rcpf_(float x) {
#if defined(__has_builtin) && __has_builtin(__builtin_amdgcn_rcpf)
  return __builtin_amdgcn_rcpf(x);
#else
  return 1.f / x;
#endif
}
__device__ __forceinline__ float sigm(float x) {
  return rcpf_(1.f + exp2f(-1.44269504088896341f * x));
}
__device__ __forceinline__ float tanh_(float x) {
  float e = exp2f(2.88539008177792681f * x);
  return 1.f - 2.f * rcpf_(e + 1.f);
}

// DPP quad_perm: 0xB1 = lane^1, 0x4E = lane^2 (within 4-lane quads)
template <int CTRL>
__device__ __forceinline__ float dppq(float v) {
  return __builtin_bit_cast(
      float, __builtin_amdgcn_update_dpp(0, __builtin_bit_cast(int, v), CTRL,
                                         0xF, 0xF, true));
}

// lgkmcnt-only barrier: keeps global (VMEM) prefetches in flight across steps
__device__ __forceinline__ void step_barrier() {
  asm volatile("s_waitcnt lgkmcnt(0)\n\ts_barrier" ::: "memory");
}

// ---------------- flags (in d_ws, zeroed each launch) ----------------
#define F_HCNT(F, li)     (F)[(li)]
#define F_XWCON(F, li)    (F)[2 + (li)]
#define F_HDONE(F, li, p) (F)[4 + (li) * PP + (p)]
#define F_XWRDY(F, li, c) (F)[16 + (li) * 128 + (c)]

__device__ __forceinline__ int aload(int* p) {
  return __hip_atomic_load(p, __ATOMIC_RELAXED, __HIP_MEMORY_SCOPE_AGENT);
}
__device__ __forceinline__ void arel(int* p, int v) {
  __hip_atomic_store(p, v, __ATOMIC_RELEASE, __HIP_MEMORY_SCOPE_AGENT);
}
__device__ __forceinline__ void acq_fence() {
  __builtin_amdgcn_fence(__ATOMIC_ACQUIRE, "agent");
}
__device__ __forceinline__ void spin_ge(int* p, int tgt) {
  unsigned n = 0;
  while (aload(p) < tgt) {
    __builtin_amdgcn_s_sleep(2);
    if (++n > 200000000u) return;  // hang guard; result will fail visibly
  }
}

// ---------------- init: transpose Wih1/2 -> WT[li][j][RPAD], biases ----------------
__global__ void lstm_init(const float* __restrict__ Wih1, const float* __restrict__ bih1,
                          const float* __restrict__ bhh1, const float* __restrict__ Wih2,
                          const float* __restrict__ bih2, const float* __restrict__ bhh2,
                          float* __restrict__ WT, float* __restrict__ BV) {
  int idx = blockIdx.x * blockDim.x + threadIdx.x;
  int stride = gridDim.x * blockDim.x;
  for (int i = idx; i < 2 * HDIM * RPAD; i += stride) {
    int li = i / (HDIM * RPAD);
    int rem = i - li * HDIM * RPAD;
    int j = rem / RPAD, r = rem - j * RPAD;
    const float* W = li ? Wih2 : Wih1;
    WT[i] = (r < GDIM) ? W[r * HDIM + j] : 0.f;
  }
  for (int i = idx; i < 2 * RPAD; i += stride) {
    int li = i >> 10, r = i & 1023;
    const float* bi = li ? bih2 : bih1;
    const float* bh = li ? bhh2 : bhh1;
    BV[i] = (r < GDIM) ? bi[r] + bh[r] : 0.f;
  }
}

// ---------------- main persistent kernel ----------------
// blocks 0..2  : recurrent WGs (layers 0,1,2). 1024 threads = 256 groups x 4
//                lanes; group g owns hidden unit u=g (all 4 gates); lane slice
//                = 64 cols. Weights: 24 NAMED uint4 in VGPRs + 8 quads LDS.
// blocks 3..10 : projection WGs.
// amdgpu_waves_per_eu(4,4): pin occupancy target to 4 waves/EU (1 WG/CU,
// which the 133 KB static LDS forces anyway) -> per-wave VGPR budget 128.
// Without the max=4 the allocator targets 8 waves/EU -> 64 regs -> spills
// the 96-reg weight set to scratch (R6/R7 evidence: VGPR_Count=64).
__global__ void __launch_bounds__(NTH)
__attribute__((amdgpu_waves_per_eu(4, 4))) lstm_main(
    const float* __restrict__ x, const float* __restrict__ Wih0,
    const float* __restrict__ bih0, const float* __restrict__ bhh0,
    const float* __restrict__ Whh0, const float* __restrict__ Whh1,
    const float* __restrict__ Whh2, const float* __restrict__ Wl,
    const float* __restrict__ bl, int* __restrict__ F,
    const float* __restrict__ WT, const float* __restrict__ BV,
    float* __restrict__ hRing, float* __restrict__ xwRing,
    float* __restrict__ out, int T) {
  __shared__ __align__(16) char smem[SMEM_BYTES];
  const int tid = threadIdx.x;
  const int bid = blockIdx.x;
  const int NC = T / CH;

  if (bid < 3) {
    // ================= recurrent role =================
    const int L = bid;
    const int u = tid >> 2, sl = tid & 3;
    const bool uok = (u < HDIM);
    const int r_abs = sl * HDIM + u;  // this lane's xw gate-row

    const float* Whh = (L == 0) ? Whh0 : (L == 1) ? Whh1 : Whh2;
    char* lw = smem + tid * 16;
#define LWADDR(lq) (lw + (size_t)(lq) * (NTH * 16))
#define ROWP(r) (uok ? (Whh + ((size_t)(r) * HDIM + u) * HDIM) : (const float*)nullptr)

    // 24 named weight quads (rows = gates i,f,g,o; k = 8-col quads 0..5)
    uint4 w00, w01, w02, w03, w04, w05;
    uint4 w10, w11, w12, w13, w14, w15;
    uint4 w20, w21, w22, w23, w24, w25;
    uint4 w30, w31, w32, w33, w34, w35;
#define INITROW(r)                                          \
  w##r##0 = pack8q(ROWP(r), sl * 64 + 0);                   \
  w##r##1 = pack8q(ROWP(r), sl * 64 + 8);                   \
  w##r##2 = pack8q(ROWP(r), sl * 64 + 16);                  \
  w##r##3 = pack8q(ROWP(r), sl * 64 + 24);                  \
  w##r##4 = pack8q(ROWP(r), sl * 64 + 32);                  \
  w##r##5 = pack8q(ROWP(r), sl * 64 + 40);                  \
  *(uint4*)LWADDR(2 * (r)) = pack8q(ROWP(r), sl * 64 + 48); \
  *(uint4*)LWADDR(2 * (r) + 1) = pack8q(ROWP(r), sl * 64 + 56);
    INITROW(0) INITROW(1) INITROW(2) INITROW(3)

    // L0 per-lane input-projection scalars (x is scalar per step)
    float w0_ = 0.f, b0_ = 0.f;
    if (L == 0 && uok) {
      w0_ = Wih0[r_abs];
      b0_ = bih0[r_abs] + bhh0[r_abs];
    }

    // zero both h buffers (incl. padded cols 250..255)
    for (int i = tid; i < (2 * HBUF) / 4; i += NTH)
      *(uint32_t*)(smem + HB_BASE + 4 * i) = 0u;
    __syncthreads();

    const float* xwBase = xwRing + (size_t)(L > 0 ? L - 1 : 0) * XRING * CH * RPAD;
    float* hBase = hRing + (size_t)L * HRING * CH * HDIM;
    float c_st = 0.f, h_last = 0.f;

    for (int tt = 0; tt < T; ++tt) {
      const int tc = tt & (CH - 1);
      const int c = tt >> 6;
      if (tc == 0) {  // chunk boundary: wait for inputs / ring backpressure
        if (tid == 0) {
          if (L > 0) spin_ge(&F_XWRDY(F, L - 1, c), 1);
          if (L < 2 && c >= HRING) {
            int cc = c - HRING;
            spin_ge(&F_HDONE(F, L, cc % PP), cc + 1);
          }
          acq_fence();
        }
        __syncthreads();
      }

      // this lane's gate input (VMEM issued early, consumed after the dot)
      float xw = 0.f;
      if (uok) {
        if (L == 0) {
          xw = fmaf(x[tt], w0_, b0_);
        } else {
          const float* xp = xwBase + (size_t)(c & (XRING - 1)) * CH * RPAD +
                            (size_t)tc * RPAD;
          xw = xp[r_abs];
        }
      }

      // dot: 4 gate rows x 64-col slice, fp16 dot2, f32 accumulate
      const char* hb = smem + HB_BASE + (tt & 1) * HBUF + sl * HSEG;
      float a0 = 0.f, a1 = 0.f, a2 = 0.f, a3 = 0.f;
#define FD4(W_, H_, A_)                \
  A_ = fdot2u((W_).x, (H_).x, A_);     \
  A_ = fdot2u((W_).y, (H_).y, A_);     \
  A_ = fdot2u((W_).z, (H_).z, A_);     \
  A_ = fdot2u((W_).w, (H_).w, A_);
#define DOTK(k)                                      \
  {                                                  \
    const uint4 hq = *(const uint4*)(hb + (k) * 16); \
    FD4(w0##k, hq, a0)                               \
    FD4(w1##k, hq, a1)                               \
    FD4(w2##k, hq, a2)                               \
    FD4(w3##k, hq, a3)                               \
  }
      DOTK(0) DOTK(1) DOTK(2) DOTK(3) DOTK(4) DOTK(5)
      {
        const uint4 hq = *(const uint4*)(hb + 96);
        uint4 q;
        q = *(const uint4*)LWADDR(0); FD4(q, hq, a0)
        q = *(const uint4*)LWADDR(2); FD4(q, hq, a1)
        q = *(const uint4*)LWADDR(4); FD4(q, hq, a2)
        q = *(const uint4*)LWADDR(6); FD4(q, hq, a3)
      }
      {
        const uint4 hq = *(const uint4*)(hb + 112);
        uint4 q;
        q = *(const uint4*)LWADDR(1); FD4(q, hq, a0)
        q = *(const uint4*)LWADDR(3); FD4(q, hq, a1)
        q = *(const uint4*)LWADDR(5); FD4(q, hq, a2)
        q = *(const uint4*)LWADDR(7); FD4(q, hq, a3)
      }

      // add xw into the gate row this lane owns, then butterfly over 4 lanes
      a0 += (sl == 0) ? xw : 0.f;
      a1 += (sl == 1) ? xw : 0.f;
      a2 += (sl == 2) ? xw : 0.f;
      a3 += (sl == 3) ? xw : 0.f;
      a0 += dppq<0xB1>(a0); a0 += dppq<0x4E>(a0);
      a1 += dppq<0xB1>(a1); a1 += dppq<0x4E>(a1);
      a2 += dppq<0xB1>(a2); a2 += dppq<0x4E>(a2);
      a3 += dppq<0xB1>(a3); a3 += dppq<0x4E>(a3);

      // update (all 4 lanes redundantly; consistent deterministic math)
      float ii = sigm(a0), ff = sigm(a1), tg = tanh_(a2), oo = sigm(a3);
      c_st = ff * c_st + ii * tg;
      float hn = oo * tanh_(c_st);
      h_last = hn;

      if (sl == 0 && uok) {
        // fp16 h into next-step buffer (segment u>>6, skewed)
        char* hw = smem + HB_BASE + ((tt + 1) & 1) * HBUF + (u >> 6) * HSEG +
                   (u & 63) * 2;
        *(_Float16*)hw = (_Float16)hn;
        if (L < 2)
          hBase[(size_t)(c & (HRING - 1)) * CH * HDIM + (size_t)tc * HDIM + u] = hn;
      }

      if (tc == CH - 1) {  // chunk end: full barrier (drains vmcnt) then publish
        __syncthreads();
        if (tid == 0) {
          if (L < 2) arel(&F_HCNT(F, L), c + 1);
          if (L > 0) arel(&F_XWCON(F, L - 1), c + 1);
        }
      } else {
        step_barrier();  // h(next) writes visible; lgkm-only
      }
    }

    if (L == 2) {  // final linear on h2[T-1]
      float* red = (float*)(smem + RED_BASE);
      if (sl == 0 && uok) red[u] = h_last;
      __syncthreads();
      if (tid == 0) {
        float s = bl[0];
        for (int j = 0; j < HDIM; ++j) s += red[j] * Wl[j];
        out[0] = s;
      }
    }
  } else {
    // ================= projection role (1024 threads, 16 waves) =================
    const int li = (bid - 3) / PP;
    const int p = (bid - 3) % PP;
    float* ldsH = (float*)smem;  // [64][257] f32
    const int lane = tid & 63, wid = tid >> 6;
    const float* WTl = WT + (size_t)li * HDIM * RPAD;
    const float* BVl = BV + (size_t)li * RPAD;

    for (int c = p; c < NC; c += PP) {
      if (tid == 0) {
        spin_ge(&F_HCNT(F, li), c + 1);
        if (c >= XRING) spin_ge(&F_XWCON(F, li), c - XRING + 1);
        acq_fence();
      }
      __syncthreads();
      const float* hsrc = hRing + (size_t)li * HRING * CH * HDIM +
                          (size_t)(c & (HRING - 1)) * CH * HDIM;
      for (int t = wid; t < CH; t += 16)
        for (int j = lane; j < HDIM; j += 64)
          ldsH[t * 257 + j] = hsrc[t * HDIM + j];
      __syncthreads();
      if (tid == 0) arel(&F_HDONE(F, li, p), c + 1);

      float* xdst = xwRing + (size_t)li * XRING * CH * RPAD +
                    (size_t)(c & (XRING - 1)) * CH * RPAD;
      const int rb0 = wid * 64;  // 16 waves x 64 rows = 1024 padded rows
      for (int grpq = 0; grpq < 8; ++grpq) {
        const int rb = rb0 + grpq * 8;
        float acc[8];
#pragma unroll
        for (int uq = 0; uq < 8; ++uq) acc[uq] = 0.f;
        const float* wp = WTl + rb;
        float4 wa4 = *(const float4*)(wp);
        float4 wb4 = *(const float4*)(wp + 4);
        for (int j = 0; j < HDIM; ++j) {
          int jn = (j + 1 < HDIM) ? j + 1 : HDIM - 1;
          float4 na = *(const float4*)(wp + (size_t)jn * RPAD);
          float4 nb = *(const float4*)(wp + (size_t)jn * RPAD + 4);
          float hj = ldsH[lane * 257 + j];
          acc[0] = fmaf(wa4.x, hj, acc[0]); acc[1] = fmaf(wa4.y, hj, acc[1]);
          acc[2] = fmaf(wa4.z, hj, acc[2]); acc[3] = fmaf(wa4.w, hj, acc[3]);
          acc[4] = fmaf(wb4.x, hj, acc[4]); acc[5] = fmaf(wb4.y, hj, acc[5]);
          acc[6] = fmaf(wb4.z, hj, acc[6]); acc[7] = fmaf(wb4.w, hj, acc[7]);
          wa4 = na; wb4 = nb;
        }
#pragma unroll
        for (int uq = 0; uq < 8; ++uq) {
          int r = rb + uq;
          if (r < GDIM) xdst[(size_t)lane * RPAD + r] = acc[uq] + BVl[r];
        }
      }
      __syncthreads();
      if (tid == 0) arel(&F_XWRDY(F, li, c), 1);
    }
  }
}

// ---------------- launch ----------------
extern "C" void kernel_launch(void* const* d_in, const int* in_sizes, int n_in,
                              void* d_out, int out_size, void* d_ws, size_t ws_size,
                              hipStream_t stream) {
  const float* x    = (const float*)d_in[0];
  const float* Wih0 = (const float*)d_in[1];
  const float* Whh0 = (const float*)d_in[2];
  const float* bih0 = (const float*)d_in[3];
  const float* bhh0 = (const float*)d_in[4];
  const float* Wih1 = (const float*)d_in[5];
  const float* Whh1 = (const float*)d_in[6];
  const float* bih1 = (const float*)d_in[7];
  const float* bhh1 = (const float*)d_in[8];
  const float* Wih2 = (const float*)d_in[9];
  const float* Whh2 = (const float*)d_in[10];
  const float* bih2 = (const float*)d_in[11];
  const float* bhh2 = (const float*)d_in[12];
  const float* Wl   = (const float*)d_in[13];
  const float* bl   = (const float*)d_in[14];
  const int T = in_sizes[0];

  char* ws = (char*)d_ws;
  int*   F   = (int*)ws;                                        // 4096 B flags
  float* WT  = (float*)(ws + 4096);                             // 2,048,000 B
  float* BV  = (float*)(ws + 4096 + 2048000);                   // 8,192 B
  float* hR  = (float*)(ws + 4096 + 2048000 + 8192);            // 512,000 B
  float* xwR = (float*)(ws + 4096 + 2048000 + 8192 + 512000);   // 2,097,152 B

  hipMemsetAsync(F, 0, 4096, stream);  // reset protocol state every call/replay
  lstm_init<<<256, 256, 0, stream>>>(Wih1, bih1, bhh1, Wih2, bih2, bhh2, WT, BV);
  lstm_main<<<3 + 2 * PP, NTH, 0, stream>>>(
      x, Wih0, bih0, bhh0, Whh0, Whh1, Whh2, Wl, bl, F, WT, BV, hR, xwR,
      (float*)d_out, T);
}